// Round 6
// baseline (338.193 us; speedup 1.0000x reference)
//
#include <hip/hip_runtime.h>
#include <hip/hip_bf16.h>
#include <math.h>

#define NCLS 40
#define H2S 64         // padded h2b row stride (ushorts) -> 128B aligned rows
#define PWG 256        // partition workgroups
#define BSH 9          // log2(nodes per bucket) = 512 nodes/bucket
#define NBMAX 512
#define SRCB 23        // src packed in low 23 bits, local node id in high 9
#define CSRCAP 14336   // staged edges per bucket (56 KB LDS)

typedef __attribute__((ext_vector_type(8))) short bf16x8;
typedef __attribute__((ext_vector_type(4))) float f32x4;

__device__ inline float bf2f(ushort u) {
    unsigned v = ((unsigned)u) << 16;
    float f;
    __builtin_memcpy(&f, &v, 4);
    return f;
}
__device__ inline ushort f2bf(float f) {
    unsigned v;
    __builtin_memcpy(&v, &f, 4);
    unsigned r = (v + 0x7FFFu + ((v >> 16) & 1u)) >> 16;
    return (ushort)r;
}

// ---------------------------------------------------------------------------
// conv_prep: blocks 0..127 transpose W1 -> bf16 W1t[64][512];
//            block 128 computes wal2/war2 (W2 @ al2 / ar2).
// ---------------------------------------------------------------------------
__global__ __launch_bounds__(256) void conv_prep_kernel(
    const float* __restrict__ W1, ushort* __restrict__ W1t,
    const float* __restrict__ W2, const float* __restrict__ al2,
    const float* __restrict__ ar2, float* __restrict__ wal2,
    float* __restrict__ war2)
{
    if (blockIdx.x < 128) {
        int id = blockIdx.x * 256 + threadIdx.x;  // 32768
        int k = id >> 6, c = id & 63;
        W1t[c * 512 + k] = f2bf(W1[k * 64 + c]);
    } else {
        int k = threadIdx.x;
        if (k < 64) {
            float a = 0.f, b = 0.f;
            for (int c = 0; c < NCLS; c++) {
                float w = W2[k * NCLS + c];
                a += w * al2[c];
                b += w * ar2[c];
            }
            wal2[k] = a;
            war2[k] = b;
        }
    }
}

// ---------------------------------------------------------------------------
// GEMM1 (MFMA, BK=64, reg-pipelined): h1b = bf16(x) @ bf16(W1).
// Epilogue computes el1/er1 from the fp32 accumulators (fused elr).
// ---------------------------------------------------------------------------
__global__ __launch_bounds__(256) void gemm1_mfma_kernel(
    const float* __restrict__ x, const ushort* __restrict__ W1t,
    const float* __restrict__ al1, const float* __restrict__ ar1,
    ushort* __restrict__ h1b, float* __restrict__ el1,
    float* __restrict__ er1, int Nn)
{
    __shared__ ushort As[64 * 72];
    __shared__ ushort Bs[64 * 72];
    const int t = threadIdx.x;
    const int lane = t & 63, w = t >> 6;
    const int tile = blockIdx.x * 64;

    f32x4 acc[4] = {};

    const int sr = t >> 2;          // 0..63 (row for A, col for B)
    const int sk = (t & 3) * 16;    // k offset 0,16,32,48
    const int arow = tile + sr;
    const bool rowok = arow < Nn;
    const float* xrow = x + (size_t)arow * 512;
    const ushort* wrow = W1t + (size_t)sr * 512;

    const int r = lane & 15, g = lane >> 4;

    // prologue: load tile k0=0 into regs
    float4 f0 = make_float4(0.f, 0.f, 0.f, 0.f), f1 = f0, f2 = f0, f3 = f0;
    bf16x8 bv0, bv1;
    if (rowok) {
        f0 = *(const float4*)(xrow + sk);
        f1 = *(const float4*)(xrow + sk + 4);
        f2 = *(const float4*)(xrow + sk + 8);
        f3 = *(const float4*)(xrow + sk + 12);
    }
    bv0 = *(const bf16x8*)(wrow + sk);
    bv1 = *(const bf16x8*)(wrow + sk + 8);

    for (int k0 = 0; k0 < 512; k0 += 64) {
        // stage regs -> LDS
        bf16x8 av0, av1;
        av0[0] = (short)f2bf(f0.x); av0[1] = (short)f2bf(f0.y);
        av0[2] = (short)f2bf(f0.z); av0[3] = (short)f2bf(f0.w);
        av0[4] = (short)f2bf(f1.x); av0[5] = (short)f2bf(f1.y);
        av0[6] = (short)f2bf(f1.z); av0[7] = (short)f2bf(f1.w);
        av1[0] = (short)f2bf(f2.x); av1[1] = (short)f2bf(f2.y);
        av1[2] = (short)f2bf(f2.z); av1[3] = (short)f2bf(f2.w);
        av1[4] = (short)f2bf(f3.x); av1[5] = (short)f2bf(f3.y);
        av1[6] = (short)f2bf(f3.z); av1[7] = (short)f2bf(f3.w);
        *(bf16x8*)&As[sr * 72 + sk] = av0;
        *(bf16x8*)&As[sr * 72 + sk + 8] = av1;
        *(bf16x8*)&Bs[sr * 72 + sk] = bv0;
        *(bf16x8*)&Bs[sr * 72 + sk + 8] = bv1;
        __syncthreads();

        // issue next tile's global loads (overlap with MFMA below)
        int k1 = k0 + 64;
        if (k1 < 512) {
            if (rowok) {
                f0 = *(const float4*)(xrow + k1 + sk);
                f1 = *(const float4*)(xrow + k1 + sk + 4);
                f2 = *(const float4*)(xrow + k1 + sk + 8);
                f3 = *(const float4*)(xrow + k1 + sk + 12);
            }
            bv0 = *(const bf16x8*)(wrow + k1 + sk);
            bv1 = *(const bf16x8*)(wrow + k1 + sk + 8);
        }

        bf16x8 af0 = *(const bf16x8*)&As[(w * 16 + r) * 72 + g * 8];
        bf16x8 af1 = *(const bf16x8*)&As[(w * 16 + r) * 72 + 32 + g * 8];
#pragma unroll
        for (int cb = 0; cb < 4; cb++) {
            bf16x8 bf0 = *(const bf16x8*)&Bs[(cb * 16 + r) * 72 + g * 8];
            acc[cb] = __builtin_amdgcn_mfma_f32_16x16x32_bf16(af0, bf0, acc[cb], 0, 0, 0);
        }
#pragma unroll
        for (int cb = 0; cb < 4; cb++) {
            bf16x8 bf1 = *(const bf16x8*)&Bs[(cb * 16 + r) * 72 + 32 + g * 8];
            acc[cb] = __builtin_amdgcn_mfma_f32_16x16x32_bf16(af1, bf1, acc[cb], 0, 0, 0);
        }
        __syncthreads();
    }

    // epilogue: store h1b + fused el1/er1 from fp32 acc.
    // lane holds col = cb*16+r of rows tile + w*16 + g*4 + v.
    float alv[4], arv[4];
#pragma unroll
    for (int cb = 0; cb < 4; cb++) {
        alv[cb] = al1[cb * 16 + r];
        arv[cb] = ar1[cb * 16 + r];
    }
#pragma unroll
    for (int v = 0; v < 4; v++) {
        int row = tile + w * 16 + g * 4 + v;
        bool ok = row < Nn;
#pragma unroll
        for (int cb = 0; cb < 4; cb++) {
            if (ok) h1b[(size_t)row * 64 + cb * 16 + r] = f2bf(acc[cb][v]);
            float pel = acc[cb][v] * alv[cb];
            float per = acc[cb][v] * arv[cb];
            pel += __shfl_xor(pel, 1); per += __shfl_xor(per, 1);
            pel += __shfl_xor(pel, 2); per += __shfl_xor(per, 2);
            pel += __shfl_xor(pel, 4); per += __shfl_xor(per, 4);
            if (ok && (r & 7) == 0) {
                int head = cb * 2 + (r >> 3);
                el1[row * 8 + head] = pel;
                er1[row * 8 + head] = per;
            }
        }
    }
}

// ---------------------------------------------------------------------------
// CSR build via radix partition over 512-node buckets.
// A) hist: per-WG LDS histogram -> hist[bucket*PWG + wg]
// ---------------------------------------------------------------------------
__global__ __launch_bounds__(256) void hist_kernel(const int* __restrict__ dst,
                                                   int* __restrict__ hist,
                                                   int Ee, int chunk, int NB)
{
    __shared__ int lh[NBMAX];
    const int wg = blockIdx.x, tid = threadIdx.x;
    for (int i = tid; i < NB; i += 256) lh[i] = 0;
    __syncthreads();
    const int beg = wg * chunk;
    const int endv = min(Ee, beg + chunk);
    for (int i = beg + tid; i < endv; i += 256) atomicAdd(&lh[dst[i] >> BSH], 1);
    __syncthreads();
    for (int b = tid; b < NB; b += 256) hist[b * PWG + wg] = lh[b];
}

// ---------------------------------------------------------------------------
// B1) scanA: per-bucket exclusive scan of its PWG-length row; total out.
// ---------------------------------------------------------------------------
__global__ __launch_bounds__(256) void scanA_kernel(int* __restrict__ hist,
                                                    int* __restrict__ bucketTot)
{
    __shared__ int s[256];
    const int b = blockIdx.x, tid = threadIdx.x;
    int v = hist[b * PWG + tid];
    s[tid] = v;
    __syncthreads();
#pragma unroll
    for (int o = 1; o < 256; o <<= 1) {
        int t = (tid >= o) ? s[tid - o] : 0;
        __syncthreads();
        s[tid] += t;
        __syncthreads();
    }
    hist[b * PWG + tid] = s[tid] - v;  // exclusive within bucket
    if (tid == 255) bucketTot[b] = s[255];
}

// ---------------------------------------------------------------------------
// B2) scanB: exclusive scan of bucket totals (NB <= 256) -> bucketBase.
// ---------------------------------------------------------------------------
__global__ __launch_bounds__(256) void scanB_kernel(const int* __restrict__ bucketTot,
                                                    int* __restrict__ bucketBase,
                                                    int NB, int Ee)
{
    __shared__ int s[256];
    const int tid = threadIdx.x;
    int v = (tid < NB) ? bucketTot[tid] : 0;
    s[tid] = v;
    __syncthreads();
#pragma unroll
    for (int o = 1; o < 256; o <<= 1) {
        int t = (tid >= o) ? s[tid - o] : 0;
        __syncthreads();
        s[tid] += t;
        __syncthreads();
    }
    if (tid < NB) bucketBase[tid] = s[tid] - v;
    if (tid == 0) bucketBase[NB] = Ee;
}

// ---------------------------------------------------------------------------
// C) partition: each WG scatters its edges (packed 4B) into its private
//    per-bucket sub-regions (LDS cursors, zero global atomics).
// ---------------------------------------------------------------------------
__global__ __launch_bounds__(256) void partition_kernel(const int* __restrict__ src,
                                                        const int* __restrict__ dst,
                                                        const int* __restrict__ hist,
                                                        const int* __restrict__ bucketBase,
                                                        unsigned* __restrict__ ebuf,
                                                        int Ee, int chunk, int NB)
{
    __shared__ int cur[NBMAX];
    const int wg = blockIdx.x, tid = threadIdx.x;
    for (int b = tid; b < NB; b += 256) cur[b] = hist[b * PWG + wg] + bucketBase[b];
    __syncthreads();
    const int beg = wg * chunk;
    const int endv = min(Ee, beg + chunk);
    for (int i = beg + tid; i < endv; i += 256) {
        int d = dst[i];
        int p = atomicAdd(&cur[d >> BSH], 1);
        ebuf[p] = ((unsigned)(d & ((1 << BSH) - 1)) << SRCB) | (unsigned)src[i];
    }
}

// ---------------------------------------------------------------------------
// D) per-bucket CSR: LDS-staged edges -> node histogram -> scan -> row_start
//    + perm_src scatter confined to the bucket's contiguous window.
// ---------------------------------------------------------------------------
__global__ __launch_bounds__(512) void bucket_csr_kernel(const unsigned* __restrict__ ebuf,
                                                         const int* __restrict__ bucketBase,
                                                         int* __restrict__ row_start,
                                                         int* __restrict__ perm_src,
                                                         int Nn, int Ee, int NB)
{
    __shared__ unsigned stage[CSRCAP];
    __shared__ int cnt[512];
    __shared__ int s[512];
    __shared__ int cur[512];
    const int b = blockIdx.x, tid = threadIdx.x;
    const int base = b << BSH;
    const int bb = bucketBase[b], be = bucketBase[b + 1];
    const int m = be - bb;

    cnt[tid] = 0;
    __syncthreads();
    for (int idx = tid; idx < m; idx += 512) {
        unsigned pk = ebuf[bb + idx];
        if (idx < CSRCAP) stage[idx] = pk;
        atomicAdd(&cnt[pk >> SRCB], 1);
    }
    __syncthreads();
    int v = cnt[tid];
    s[tid] = v;
    __syncthreads();
#pragma unroll
    for (int o = 1; o < 512; o <<= 1) {
        int t = (tid >= o) ? s[tid - o] : 0;
        __syncthreads();
        s[tid] += t;
        __syncthreads();
    }
    const int off = bb + s[tid] - v;
    const int node = base + tid;
    if (node < Nn) row_start[node] = off;
    cur[tid] = off;
    __syncthreads();
    for (int idx = tid; idx < m; idx += 512) {
        unsigned pk = (idx < CSRCAP) ? stage[idx] : ebuf[bb + idx];
        int p = atomicAdd(&cur[pk >> SRCB], 1);
        perm_src[p] = (int)(pk & ((1u << SRCB) - 1u));
    }
    if (b == NB - 1 && tid == 0) row_start[Nn] = Ee;
}

// ---------------------------------------------------------------------------
// agg1: one wave per dst node, lane = h*8+d. Masked 16-deep gather batches.
// ---------------------------------------------------------------------------
__global__ __launch_bounds__(256) void agg1_kernel(
    const ushort* __restrict__ h1b, const float* __restrict__ el1,
    const float* __restrict__ er1, const int* __restrict__ row_start,
    const int* __restrict__ perm_src, const float* __restrict__ b1,
    ushort* __restrict__ hmidb, int Nn)
{
    int wid = (blockIdx.x * blockDim.x + threadIdx.x) >> 6;
    int lane = threadIdx.x & 63;
    if (wid >= Nn) return;
    const int h = lane >> 3;
    const int beg = row_start[wid], end = row_start[wid + 1];
    const float er = er1[wid * 8 + h];

    float acc = 0.f, denom = 0.f;
    for (int i0 = beg; i0 < end; i0 += 64) {
        const int cnt = min(end - i0, 64);
        int pv = (i0 + lane < end) ? perm_src[i0 + lane] : 0;
        for (int j = 0; j < cnt; j += 16) {
            int ss[16];
            float ev[16];
            ushort rv[16];
#pragma unroll
            for (int u = 0; u < 16; u++) ss[u] = __shfl(pv, min(j + u, cnt - 1));
#pragma unroll
            for (int u = 0; u < 16; u++) ev[u] = el1[ss[u] * 8 + h];
#pragma unroll
            for (int u = 0; u < 16; u++) rv[u] = h1b[(size_t)ss[u] * 64 + lane];
#pragma unroll
            for (int u = 0; u < 16; u++) {
                float e = ev[u] + er;
                e = (e >= 0.f) ? e : 0.2f * e;
                float wgt = (j + u < cnt) ? __expf(fminf(e, 80.f)) : 0.f;
                denom += wgt;
                acc += bf2f(rv[u]) * wgt;
            }
        }
    }
    float v = acc / (denom + 1e-9f) + b1[lane];
    v = (v > 0.f) ? v : expm1f(v);  // ELU
    hmidb[(size_t)wid * 64 + lane] = f2bf(v);
}

// ---------------------------------------------------------------------------
// GEMM2: h2b = hmid @ W2 (bf16 in, bf16 out, padded rows) + el2/er2.
// ---------------------------------------------------------------------------
__global__ __launch_bounds__(256) void gemm2_kernel(
    const ushort* __restrict__ hmidb, const float* __restrict__ W2,
    const float* __restrict__ wal2, const float* __restrict__ war2,
    ushort* __restrict__ h2b, float* __restrict__ el2, float* __restrict__ er2,
    int Nn)
{
    __shared__ float w2s[64 * NCLS];
    __shared__ float wals[64], wars[64];
    for (int i = threadIdx.x; i < 64 * NCLS; i += blockDim.x) w2s[i] = W2[i];
    if (threadIdx.x < 64) {
        wals[threadIdx.x] = wal2[threadIdx.x];
        wars[threadIdx.x] = war2[threadIdx.x];
    }
    __syncthreads();
    int n = blockIdx.x * blockDim.x + threadIdx.x;
    if (n >= Nn) return;

    float out[NCLS];
#pragma unroll
    for (int c = 0; c < NCLS; c++) out[c] = 0.f;
    float accel = 0.f, accer = 0.f;

#pragma unroll 4
    for (int k4 = 0; k4 < 16; k4++) {
        ushort4 u = *(const ushort4*)&hmidb[(size_t)n * 64 + k4 * 4];
        float h0 = bf2f(u.x), h1 = bf2f(u.y), h2 = bf2f(u.z), h3 = bf2f(u.w);
        accel += h0 * wals[k4 * 4] + h1 * wals[k4 * 4 + 1] + h2 * wals[k4 * 4 + 2] + h3 * wals[k4 * 4 + 3];
        accer += h0 * wars[k4 * 4] + h1 * wars[k4 * 4 + 1] + h2 * wars[k4 * 4 + 2] + h3 * wars[k4 * 4 + 3];
#pragma unroll
        for (int c = 0; c < NCLS; c++) {
            out[c] += h0 * w2s[(k4 * 4 + 0) * NCLS + c] + h1 * w2s[(k4 * 4 + 1) * NCLS + c] +
                      h2 * w2s[(k4 * 4 + 2) * NCLS + c] + h3 * w2s[(k4 * 4 + 3) * NCLS + c];
        }
    }
    el2[n] = accel;
    er2[n] = accer;
#pragma unroll
    for (int c = 0; c < NCLS; c++) h2b[(size_t)n * H2S + c] = f2bf(out[c]);
}

// ---------------------------------------------------------------------------
// agg2 + log_softmax: one wave per dst node; lane = class. Masked 16-batches.
// ---------------------------------------------------------------------------
__global__ __launch_bounds__(256) void agg2_kernel(
    const ushort* __restrict__ h2b, const float* __restrict__ el2,
    const float* __restrict__ er2, const int* __restrict__ row_start,
    const int* __restrict__ perm_src, const float* __restrict__ b2,
    float* __restrict__ out, int Nn)
{
    int wid = (blockIdx.x * blockDim.x + threadIdx.x) >> 6;
    int lane = threadIdx.x & 63;
    if (wid >= Nn) return;
    const int beg = row_start[wid], end = row_start[wid + 1];
    const float er = er2[wid];
    const bool act = lane < NCLS;
    const int cl = act ? lane : 0;

    float acc = 0.f, denom = 0.f;
    for (int i0 = beg; i0 < end; i0 += 64) {
        const int cnt = min(end - i0, 64);
        int pv = (i0 + lane < end) ? perm_src[i0 + lane] : 0;
        for (int j = 0; j < cnt; j += 16) {
            int ss[16];
            float ev[16];
            ushort rv[16];
#pragma unroll
            for (int u = 0; u < 16; u++) ss[u] = __shfl(pv, min(j + u, cnt - 1));
#pragma unroll
            for (int u = 0; u < 16; u++) ev[u] = el2[ss[u]];
#pragma unroll
            for (int u = 0; u < 16; u++) rv[u] = h2b[(size_t)ss[u] * H2S + cl];
#pragma unroll
            for (int u = 0; u < 16; u++) {
                float e = ev[u] + er;
                e = (e >= 0.f) ? e : 0.2f * e;
                float wgt = (j + u < cnt) ? __expf(fminf(e, 80.f)) : 0.f;
                denom += wgt;
                acc += bf2f(rv[u]) * wgt;
            }
        }
    }
    float v = act ? (acc / (denom + 1e-9f) + b2[lane]) : -1e30f;

    float mx = v;
#pragma unroll
    for (int o = 1; o < 64; o <<= 1) mx = fmaxf(mx, __shfl_xor(mx, o));
    float sx = act ? __expf(v - mx) : 0.f;
#pragma unroll
    for (int o = 1; o < 64; o <<= 1) sx += __shfl_xor(sx, o);
    if (act) out[(size_t)wid * NCLS + lane] = v - mx - __logf(sx);
}

// ---------------------------------------------------------------------------
extern "C" void kernel_launch(void* const* d_in, const int* in_sizes, int n_in,
                              void* d_out, int out_size, void* d_ws, size_t ws_size,
                              hipStream_t stream)
{
    const float* x   = (const float*)d_in[0];
    const int*   src = (const int*)d_in[1];
    const int*   dst = (const int*)d_in[2];
    const float* W1  = (const float*)d_in[3];
    const float* al1 = (const float*)d_in[4];
    const float* ar1 = (const float*)d_in[5];
    const float* b1  = (const float*)d_in[6];
    const float* W2  = (const float*)d_in[7];
    const float* al2 = (const float*)d_in[8];
    const float* ar2 = (const float*)d_in[9];
    const float* b2  = (const float*)d_in[10];
    float* out = (float*)d_out;

    const int Nn = in_sizes[0] / 512;
    const int Ee = in_sizes[1];
    const int NB = (Nn + (1 << BSH) - 1) >> BSH;   // buckets of 512 nodes
    const int chunk = (Ee + PWG - 1) / PWG;

    // workspace layout (16B-aligned bump allocator)
    char* wsb = (char*)d_ws;
    size_t off = 0;
    auto alloc = [&](size_t bytes) -> void* {
        off = (off + 15) & ~(size_t)15;
        void* p = wsb + off;
        off += bytes;
        return p;
    };
    ushort* h1b   = (ushort*)alloc((size_t)Nn * 64 * 2);
    ushort* hmidb = (ushort*)alloc((size_t)Nn * 64 * 2);
    ushort* h2b   = (ushort*)alloc((size_t)Nn * H2S * 2);
    ushort* W1t   = (ushort*)alloc(64 * 512 * 2);
    float* el1  = (float*)alloc((size_t)Nn * 8 * 4);
    float* er1  = (float*)alloc((size_t)Nn * 8 * 4);
    float* el2  = (float*)alloc((size_t)Nn * 4);
    float* er2  = (float*)alloc((size_t)Nn * 4);
    float* wal2 = (float*)alloc(64 * 4);
    float* war2 = (float*)alloc(64 * 4);
    int* row_start  = (int*)alloc((size_t)(Nn + 1) * 4);
    int* hist       = (int*)alloc((size_t)NB * PWG * 4);
    int* bucketTot  = (int*)alloc((size_t)NB * 4);
    int* bucketBase = (int*)alloc((size_t)(NB + 1) * 4);
    int* perm_src   = (int*)alloc((size_t)Ee * 4);
    unsigned* ebuf  = (unsigned*)alloc((size_t)Ee * 4);

    // CSR build (radix partition, no global atomics, hierarchical scan)
    hist_kernel<<<PWG, 256, 0, stream>>>(dst, hist, Ee, chunk, NB);
    scanA_kernel<<<NB, 256, 0, stream>>>(hist, bucketTot);
    scanB_kernel<<<1, 256, 0, stream>>>(bucketTot, bucketBase, NB, Ee);
    partition_kernel<<<PWG, 256, 0, stream>>>(src, dst, hist, bucketBase, ebuf, Ee, chunk, NB);
    bucket_csr_kernel<<<NB, 512, 0, stream>>>(ebuf, bucketBase, row_start, perm_src, Nn, Ee, NB);

    // layer 1
    conv_prep_kernel<<<129, 256, 0, stream>>>(W1, W1t, W2, al2, ar2, wal2, war2);
    gemm1_mfma_kernel<<<(Nn + 63) / 64, 256, 0, stream>>>(x, W1t, al1, ar1, h1b, el1, er1, Nn);
    agg1_kernel<<<(Nn + 3) / 4, 256, 0, stream>>>(h1b, el1, er1, row_start, perm_src, b1, hmidb, Nn);

    // layer 2
    gemm2_kernel<<<(Nn + 255) / 256, 256, 0, stream>>>(hmidb, W2, wal2, war2, h2b, el2, er2, Nn);
    agg2_kernel<<<(Nn + 3) / 4, 256, 0, stream>>>(h2b, el2, er2, row_start, perm_src, b2, out, Nn);
}

// Round 7
// 264.366 us; speedup vs baseline: 1.2793x; 1.2793x over previous
//
#include <hip/hip_runtime.h>
#include <hip/hip_bf16.h>
#include <math.h>

#define NCLS 40
#define PWG 256        // partition workgroups
#define BSH 9          // log2(nodes per bucket) = 512 nodes/bucket
#define NBMAX 512
#define SRCB 23        // src packed in low 23 bits, local node id in high 9
#define CSRCAP 14336   // staged edges per bucket (56 KB LDS)

typedef __attribute__((ext_vector_type(8))) short bf16x8;
typedef __attribute__((ext_vector_type(4))) float f32x4;

__device__ inline float bf2f(ushort u) {
    unsigned v = ((unsigned)u) << 16;
    float f;
    __builtin_memcpy(&f, &v, 4);
    return f;
}
__device__ inline ushort f2bf(float f) {
    unsigned v;
    __builtin_memcpy(&v, &f, 4);
    unsigned r = (v + 0x7FFFu + ((v >> 16) & 1u)) >> 16;
    return (ushort)r;
}

// ---------------------------------------------------------------------------
// conv_prep: blocks 0..127 transpose W1 -> bf16 W1t[64][512];
//            block 128 computes wal2/war2 (W2 @ al2 / ar2).
// ---------------------------------------------------------------------------
__global__ __launch_bounds__(256) void conv_prep_kernel(
    const float* __restrict__ W1, ushort* __restrict__ W1t,
    const float* __restrict__ W2, const float* __restrict__ al2,
    const float* __restrict__ ar2, float* __restrict__ wal2,
    float* __restrict__ war2)
{
    if (blockIdx.x < 128) {
        int id = blockIdx.x * 256 + threadIdx.x;  // 32768
        int k = id >> 6, c = id & 63;
        W1t[c * 512 + k] = f2bf(W1[k * 64 + c]);
    } else {
        int k = threadIdx.x;
        if (k < 64) {
            float a = 0.f, b = 0.f;
            for (int c = 0; c < NCLS; c++) {
                float w = W2[k * NCLS + c];
                a += w * al2[c];
                b += w * ar2[c];
            }
            wal2[k] = a;
            war2[k] = b;
        }
    }
}

// ---------------------------------------------------------------------------
// GEMM1 (MFMA, BK=64, reg-pipelined): h1b = bf16(x) @ bf16(W1).
// Epilogue computes el1/er1 from the fp32 accumulators (fused elr).
// ---------------------------------------------------------------------------
__global__ __launch_bounds__(256) void gemm1_mfma_kernel(
    const float* __restrict__ x, const ushort* __restrict__ W1t,
    const float* __restrict__ al1, const float* __restrict__ ar1,
    ushort* __restrict__ h1b, float* __restrict__ el1,
    float* __restrict__ er1, int Nn)
{
    __shared__ ushort As[64 * 72];
    __shared__ ushort Bs[64 * 72];
    const int t = threadIdx.x;
    const int lane = t & 63, w = t >> 6;
    const int tile = blockIdx.x * 64;

    f32x4 acc[4] = {};

    const int sr = t >> 2;          // 0..63 (row for A, col for B)
    const int sk = (t & 3) * 16;    // k offset 0,16,32,48
    const int arow = tile + sr;
    const bool rowok = arow < Nn;
    const float* xrow = x + (size_t)arow * 512;
    const ushort* wrow = W1t + (size_t)sr * 512;

    const int r = lane & 15, g = lane >> 4;

    // prologue: load tile k0=0 into regs
    float4 f0 = make_float4(0.f, 0.f, 0.f, 0.f), f1 = f0, f2 = f0, f3 = f0;
    bf16x8 bv0, bv1;
    if (rowok) {
        f0 = *(const float4*)(xrow + sk);
        f1 = *(const float4*)(xrow + sk + 4);
        f2 = *(const float4*)(xrow + sk + 8);
        f3 = *(const float4*)(xrow + sk + 12);
    }
    bv0 = *(const bf16x8*)(wrow + sk);
    bv1 = *(const bf16x8*)(wrow + sk + 8);

    for (int k0 = 0; k0 < 512; k0 += 64) {
        // stage regs -> LDS
        bf16x8 av0, av1;
        av0[0] = (short)f2bf(f0.x); av0[1] = (short)f2bf(f0.y);
        av0[2] = (short)f2bf(f0.z); av0[3] = (short)f2bf(f0.w);
        av0[4] = (short)f2bf(f1.x); av0[5] = (short)f2bf(f1.y);
        av0[6] = (short)f2bf(f1.z); av0[7] = (short)f2bf(f1.w);
        av1[0] = (short)f2bf(f2.x); av1[1] = (short)f2bf(f2.y);
        av1[2] = (short)f2bf(f2.z); av1[3] = (short)f2bf(f2.w);
        av1[4] = (short)f2bf(f3.x); av1[5] = (short)f2bf(f3.y);
        av1[6] = (short)f2bf(f3.z); av1[7] = (short)f2bf(f3.w);
        *(bf16x8*)&As[sr * 72 + sk] = av0;
        *(bf16x8*)&As[sr * 72 + sk + 8] = av1;
        *(bf16x8*)&Bs[sr * 72 + sk] = bv0;
        *(bf16x8*)&Bs[sr * 72 + sk + 8] = bv1;
        __syncthreads();

        // issue next tile's global loads (overlap with MFMA below)
        int k1 = k0 + 64;
        if (k1 < 512) {
            if (rowok) {
                f0 = *(const float4*)(xrow + k1 + sk);
                f1 = *(const float4*)(xrow + k1 + sk + 4);
                f2 = *(const float4*)(xrow + k1 + sk + 8);
                f3 = *(const float4*)(xrow + k1 + sk + 12);
            }
            bv0 = *(const bf16x8*)(wrow + k1 + sk);
            bv1 = *(const bf16x8*)(wrow + k1 + sk + 8);
        }

        bf16x8 af0 = *(const bf16x8*)&As[(w * 16 + r) * 72 + g * 8];
        bf16x8 af1 = *(const bf16x8*)&As[(w * 16 + r) * 72 + 32 + g * 8];
#pragma unroll
        for (int cb = 0; cb < 4; cb++) {
            bf16x8 bf0 = *(const bf16x8*)&Bs[(cb * 16 + r) * 72 + g * 8];
            acc[cb] = __builtin_amdgcn_mfma_f32_16x16x32_bf16(af0, bf0, acc[cb], 0, 0, 0);
        }
#pragma unroll
        for (int cb = 0; cb < 4; cb++) {
            bf16x8 bf1 = *(const bf16x8*)&Bs[(cb * 16 + r) * 72 + 32 + g * 8];
            acc[cb] = __builtin_amdgcn_mfma_f32_16x16x32_bf16(af1, bf1, acc[cb], 0, 0, 0);
        }
        __syncthreads();
    }

    // epilogue: store h1b + fused el1/er1 from fp32 acc.
    // lane holds col = cb*16+r of rows tile + w*16 + g*4 + v.
    float alv[4], arv[4];
#pragma unroll
    for (int cb = 0; cb < 4; cb++) {
        alv[cb] = al1[cb * 16 + r];
        arv[cb] = ar1[cb * 16 + r];
    }
#pragma unroll
    for (int v = 0; v < 4; v++) {
        int row = tile + w * 16 + g * 4 + v;
        bool ok = row < Nn;
#pragma unroll
        for (int cb = 0; cb < 4; cb++) {
            if (ok) h1b[(size_t)row * 64 + cb * 16 + r] = f2bf(acc[cb][v]);
            float pel = acc[cb][v] * alv[cb];
            float per = acc[cb][v] * arv[cb];
            pel += __shfl_xor(pel, 1); per += __shfl_xor(per, 1);
            pel += __shfl_xor(pel, 2); per += __shfl_xor(per, 2);
            pel += __shfl_xor(pel, 4); per += __shfl_xor(per, 4);
            if (ok && (r & 7) == 0) {
                int head = cb * 2 + (r >> 3);
                el1[row * 8 + head] = pel;
                er1[row * 8 + head] = per;
            }
        }
    }
}

// ---------------------------------------------------------------------------
// CSR build via radix partition over 512-node buckets.
// A) hist: per-WG LDS histogram -> hist[bucket*PWG + wg]
// ---------------------------------------------------------------------------
__global__ __launch_bounds__(256) void hist_kernel(const int* __restrict__ dst,
                                                   int* __restrict__ hist,
                                                   int Ee, int chunk, int NB)
{
    __shared__ int lh[NBMAX];
    const int wg = blockIdx.x, tid = threadIdx.x;
    for (int i = tid; i < NB; i += 256) lh[i] = 0;
    __syncthreads();
    const int beg = wg * chunk;
    const int endv = min(Ee, beg + chunk);
    for (int i = beg + tid; i < endv; i += 256) atomicAdd(&lh[dst[i] >> BSH], 1);
    __syncthreads();
    for (int b = tid; b < NB; b += 256) hist[b * PWG + wg] = lh[b];
}

// ---------------------------------------------------------------------------
// B1) scanA: per-bucket exclusive scan of its PWG-length row; total out.
// ---------------------------------------------------------------------------
__global__ __launch_bounds__(256) void scanA_kernel(int* __restrict__ hist,
                                                    int* __restrict__ bucketTot)
{
    __shared__ int s[256];
    const int b = blockIdx.x, tid = threadIdx.x;
    int v = hist[b * PWG + tid];
    s[tid] = v;
    __syncthreads();
#pragma unroll
    for (int o = 1; o < 256; o <<= 1) {
        int t = (tid >= o) ? s[tid - o] : 0;
        __syncthreads();
        s[tid] += t;
        __syncthreads();
    }
    hist[b * PWG + tid] = s[tid] - v;  // exclusive within bucket
    if (tid == 255) bucketTot[b] = s[255];
}

// ---------------------------------------------------------------------------
// B2) scanB: exclusive scan of bucket totals (NB <= 256) -> bucketBase.
// ---------------------------------------------------------------------------
__global__ __launch_bounds__(256) void scanB_kernel(const int* __restrict__ bucketTot,
                                                    int* __restrict__ bucketBase,
                                                    int NB, int Ee)
{
    __shared__ int s[256];
    const int tid = threadIdx.x;
    int v = (tid < NB) ? bucketTot[tid] : 0;
    s[tid] = v;
    __syncthreads();
#pragma unroll
    for (int o = 1; o < 256; o <<= 1) {
        int t = (tid >= o) ? s[tid - o] : 0;
        __syncthreads();
        s[tid] += t;
        __syncthreads();
    }
    if (tid < NB) bucketBase[tid] = s[tid] - v;
    if (tid == 0) bucketBase[NB] = Ee;
}

// ---------------------------------------------------------------------------
// C) partition: each WG scatters its edges (packed 4B) into its private
//    per-bucket sub-regions (LDS cursors, zero global atomics).
// ---------------------------------------------------------------------------
__global__ __launch_bounds__(256) void partition_kernel(const int* __restrict__ src,
                                                        const int* __restrict__ dst,
                                                        const int* __restrict__ hist,
                                                        const int* __restrict__ bucketBase,
                                                        unsigned* __restrict__ ebuf,
                                                        int Ee, int chunk, int NB)
{
    __shared__ int cur[NBMAX];
    const int wg = blockIdx.x, tid = threadIdx.x;
    for (int b = tid; b < NB; b += 256) cur[b] = hist[b * PWG + wg] + bucketBase[b];
    __syncthreads();
    const int beg = wg * chunk;
    const int endv = min(Ee, beg + chunk);
    for (int i = beg + tid; i < endv; i += 256) {
        int d = dst[i];
        int p = atomicAdd(&cur[d >> BSH], 1);
        ebuf[p] = ((unsigned)(d & ((1 << BSH) - 1)) << SRCB) | (unsigned)src[i];
    }
}

// ---------------------------------------------------------------------------
// D) per-bucket CSR: LDS-staged edges -> node histogram -> scan -> row_start
//    + perm_src scatter confined to the bucket's contiguous window.
// ---------------------------------------------------------------------------
__global__ __launch_bounds__(512) void bucket_csr_kernel(const unsigned* __restrict__ ebuf,
                                                         const int* __restrict__ bucketBase,
                                                         int* __restrict__ row_start,
                                                         int* __restrict__ perm_src,
                                                         int Nn, int Ee, int NB)
{
    __shared__ unsigned stage[CSRCAP];
    __shared__ int cnt[512];
    __shared__ int s[512];
    __shared__ int cur[512];
    const int b = blockIdx.x, tid = threadIdx.x;
    const int base = b << BSH;
    const int bb = bucketBase[b], be = bucketBase[b + 1];
    const int m = be - bb;

    cnt[tid] = 0;
    __syncthreads();
    for (int idx = tid; idx < m; idx += 512) {
        unsigned pk = ebuf[bb + idx];
        if (idx < CSRCAP) stage[idx] = pk;
        atomicAdd(&cnt[pk >> SRCB], 1);
    }
    __syncthreads();
    int v = cnt[tid];
    s[tid] = v;
    __syncthreads();
#pragma unroll
    for (int o = 1; o < 512; o <<= 1) {
        int t = (tid >= o) ? s[tid - o] : 0;
        __syncthreads();
        s[tid] += t;
        __syncthreads();
    }
    const int off = bb + s[tid] - v;
    const int node = base + tid;
    if (node < Nn) row_start[node] = off;
    cur[tid] = off;
    __syncthreads();
    for (int idx = tid; idx < m; idx += 512) {
        unsigned pk = (idx < CSRCAP) ? stage[idx] : ebuf[bb + idx];
        int p = atomicAdd(&cur[pk >> SRCB], 1);
        perm_src[p] = (int)(pk & ((1u << SRCB) - 1u));
    }
    if (b == NB - 1 && tid == 0) row_start[Nn] = Ee;
}

// ---------------------------------------------------------------------------
// agg1: one wave per dst node, lane = h*8+d. Single pass, 8/4/1 batches.
// ---------------------------------------------------------------------------
__global__ __launch_bounds__(256) void agg1_kernel(
    const ushort* __restrict__ h1b, const float* __restrict__ el1,
    const float* __restrict__ er1, const int* __restrict__ row_start,
    const int* __restrict__ perm_src, const float* __restrict__ b1,
    ushort* __restrict__ hmidb, int Nn)
{
    int wid = (blockIdx.x * blockDim.x + threadIdx.x) >> 6;
    int lane = threadIdx.x & 63;
    if (wid >= Nn) return;
    const int h = lane >> 3;
    const int beg = row_start[wid], end = row_start[wid + 1];
    const float er = er1[wid * 8 + h];

    float acc = 0.f, denom = 0.f;
    for (int i0 = beg; i0 < end; i0 += 64) {
        int cnt = min(end - i0, 64);
        int pv = (i0 + lane < end) ? perm_src[i0 + lane] : 0;
        int j = 0;
        for (; j + 8 <= cnt; j += 8) {
            int ss[8];
#pragma unroll
            for (int u = 0; u < 8; u++) ss[u] = __shfl(pv, j + u);
            float ev[8];
            ushort rv[8];
#pragma unroll
            for (int u = 0; u < 8; u++) ev[u] = el1[ss[u] * 8 + h];
#pragma unroll
            for (int u = 0; u < 8; u++) rv[u] = h1b[(size_t)ss[u] * 64 + lane];
#pragma unroll
            for (int u = 0; u < 8; u++) {
                float e = ev[u] + er;
                e = (e >= 0.f) ? e : 0.2f * e;
                float w = __expf(fminf(e, 80.f));
                denom += w;
                acc += bf2f(rv[u]) * w;
            }
        }
        for (; j + 4 <= cnt; j += 4) {
            int ss[4];
#pragma unroll
            for (int u = 0; u < 4; u++) ss[u] = __shfl(pv, j + u);
            float ev[4];
            ushort rv[4];
#pragma unroll
            for (int u = 0; u < 4; u++) ev[u] = el1[ss[u] * 8 + h];
#pragma unroll
            for (int u = 0; u < 4; u++) rv[u] = h1b[(size_t)ss[u] * 64 + lane];
#pragma unroll
            for (int u = 0; u < 4; u++) {
                float e = ev[u] + er;
                e = (e >= 0.f) ? e : 0.2f * e;
                float w = __expf(fminf(e, 80.f));
                denom += w;
                acc += bf2f(rv[u]) * w;
            }
        }
        for (; j < cnt; j++) {
            int sI = __shfl(pv, j);
            float e = el1[sI * 8 + h] + er;
            e = (e >= 0.f) ? e : 0.2f * e;
            float w = __expf(fminf(e, 80.f));
            denom += w;
            acc += bf2f(h1b[(size_t)sI * 64 + lane]) * w;
        }
    }
    float v = acc / (denom + 1e-9f) + b1[lane];
    v = (v > 0.f) ? v : expm1f(v);  // ELU
    hmidb[(size_t)wid * 64 + lane] = f2bf(v);
}

// ---------------------------------------------------------------------------
// GEMM2: h2b = hmid @ W2 (bf16 in, bf16 out) + el2/er2. One thread per node.
// ---------------------------------------------------------------------------
__global__ __launch_bounds__(256) void gemm2_kernel(
    const ushort* __restrict__ hmidb, const float* __restrict__ W2,
    const float* __restrict__ wal2, const float* __restrict__ war2,
    ushort* __restrict__ h2b, float* __restrict__ el2, float* __restrict__ er2,
    int Nn)
{
    __shared__ float w2s[64 * NCLS];
    __shared__ float wals[64], wars[64];
    for (int i = threadIdx.x; i < 64 * NCLS; i += blockDim.x) w2s[i] = W2[i];
    if (threadIdx.x < 64) {
        wals[threadIdx.x] = wal2[threadIdx.x];
        wars[threadIdx.x] = war2[threadIdx.x];
    }
    __syncthreads();
    int n = blockIdx.x * blockDim.x + threadIdx.x;
    if (n >= Nn) return;

    float out[NCLS];
#pragma unroll
    for (int c = 0; c < NCLS; c++) out[c] = 0.f;
    float accel = 0.f, accer = 0.f;

#pragma unroll 4
    for (int k4 = 0; k4 < 16; k4++) {
        ushort4 u = *(const ushort4*)&hmidb[(size_t)n * 64 + k4 * 4];
        float h0 = bf2f(u.x), h1 = bf2f(u.y), h2 = bf2f(u.z), h3 = bf2f(u.w);
        accel += h0 * wals[k4 * 4] + h1 * wals[k4 * 4 + 1] + h2 * wals[k4 * 4 + 2] + h3 * wals[k4 * 4 + 3];
        accer += h0 * wars[k4 * 4] + h1 * wars[k4 * 4 + 1] + h2 * wars[k4 * 4 + 2] + h3 * wars[k4 * 4 + 3];
#pragma unroll
        for (int c = 0; c < NCLS; c++) {
            out[c] += h0 * w2s[(k4 * 4 + 0) * NCLS + c] + h1 * w2s[(k4 * 4 + 1) * NCLS + c] +
                      h2 * w2s[(k4 * 4 + 2) * NCLS + c] + h3 * w2s[(k4 * 4 + 3) * NCLS + c];
        }
    }
    el2[n] = accel;
    er2[n] = accer;
#pragma unroll
    for (int c = 0; c < NCLS; c++) h2b[(size_t)n * NCLS + c] = f2bf(out[c]);
}

// ---------------------------------------------------------------------------
// agg2 + log_softmax: one wave per dst node; lane = class. 8/4/1 batches.
// ---------------------------------------------------------------------------
__global__ __launch_bounds__(256) void agg2_kernel(
    const ushort* __restrict__ h2b, const float* __restrict__ el2,
    const float* __restrict__ er2, const int* __restrict__ row_start,
    const int* __restrict__ perm_src, const float* __restrict__ b2,
    float* __restrict__ out, int Nn)
{
    int wid = (blockIdx.x * blockDim.x + threadIdx.x) >> 6;
    int lane = threadIdx.x & 63;
    if (wid >= Nn) return;
    const int beg = row_start[wid], end = row_start[wid + 1];
    const float er = er2[wid];
    const bool act = lane < NCLS;
    const int cl = act ? lane : 0;

    float acc = 0.f, denom = 0.f;
    for (int i0 = beg; i0 < end; i0 += 64) {
        int cnt = min(end - i0, 64);
        int pv = (i0 + lane < end) ? perm_src[i0 + lane] : 0;
        int j = 0;
        for (; j + 8 <= cnt; j += 8) {
            int ss[8];
#pragma unroll
            for (int u = 0; u < 8; u++) ss[u] = __shfl(pv, j + u);
            float ev[8];
            ushort rv[8];
#pragma unroll
            for (int u = 0; u < 8; u++) ev[u] = el2[ss[u]];
#pragma unroll
            for (int u = 0; u < 8; u++) rv[u] = h2b[(size_t)ss[u] * NCLS + cl];
#pragma unroll
            for (int u = 0; u < 8; u++) {
                float e = ev[u] + er;
                e = (e >= 0.f) ? e : 0.2f * e;
                float w = __expf(fminf(e, 80.f));
                denom += w;
                acc += bf2f(rv[u]) * w;
            }
        }
        for (; j + 4 <= cnt; j += 4) {
            int ss[4];
#pragma unroll
            for (int u = 0; u < 4; u++) ss[u] = __shfl(pv, j + u);
            float ev[4];
            ushort rv[4];
#pragma unroll
            for (int u = 0; u < 4; u++) ev[u] = el2[ss[u]];
#pragma unroll
            for (int u = 0; u < 4; u++) rv[u] = h2b[(size_t)ss[u] * NCLS + cl];
#pragma unroll
            for (int u = 0; u < 4; u++) {
                float e = ev[u] + er;
                e = (e >= 0.f) ? e : 0.2f * e;
                float w = __expf(fminf(e, 80.f));
                denom += w;
                acc += bf2f(rv[u]) * w;
            }
        }
        for (; j < cnt; j++) {
            int sI = __shfl(pv, j);
            float e = el2[sI] + er;
            e = (e >= 0.f) ? e : 0.2f * e;
            float w = __expf(fminf(e, 80.f));
            denom += w;
            acc += bf2f(h2b[(size_t)sI * NCLS + cl]) * w;
        }
    }
    float v = act ? (acc / (denom + 1e-9f) + b2[lane]) : -1e30f;

    float mx = v;
#pragma unroll
    for (int o = 1; o < 64; o <<= 1) mx = fmaxf(mx, __shfl_xor(mx, o));
    float sx = act ? __expf(v - mx) : 0.f;
#pragma unroll
    for (int o = 1; o < 64; o <<= 1) sx += __shfl_xor(sx, o);
    if (act) out[(size_t)wid * NCLS + lane] = v - mx - __logf(sx);
}

// ---------------------------------------------------------------------------
extern "C" void kernel_launch(void* const* d_in, const int* in_sizes, int n_in,
                              void* d_out, int out_size, void* d_ws, size_t ws_size,
                              hipStream_t stream)
{
    const float* x   = (const float*)d_in[0];
    const int*   src = (const int*)d_in[1];
    const int*   dst = (const int*)d_in[2];
    const float* W1  = (const float*)d_in[3];
    const float* al1 = (const float*)d_in[4];
    const float* ar1 = (const float*)d_in[5];
    const float* b1  = (const float*)d_in[6];
    const float* W2  = (const float*)d_in[7];
    const float* al2 = (const float*)d_in[8];
    const float* ar2 = (const float*)d_in[9];
    const float* b2  = (const float*)d_in[10];
    float* out = (float*)d_out;

    const int Nn = in_sizes[0] / 512;
    const int Ee = in_sizes[1];
    const int NB = (Nn + (1 << BSH) - 1) >> BSH;   // buckets of 512 nodes
    const int chunk = (Ee + PWG - 1) / PWG;

    // workspace layout (16B-aligned bump allocator)
    char* wsb = (char*)d_ws;
    size_t off = 0;
    auto alloc = [&](size_t bytes) -> void* {
        off = (off + 15) & ~(size_t)15;
        void* p = wsb + off;
        off += bytes;
        return p;
    };
    ushort* h1b   = (ushort*)alloc((size_t)Nn * 64 * 2);
    ushort* hmidb = (ushort*)alloc((size_t)Nn * 64 * 2);
    ushort* h2b   = (ushort*)alloc((size_t)Nn * NCLS * 2);
    ushort* W1t   = (ushort*)alloc(64 * 512 * 2);
    float* el1  = (float*)alloc((size_t)Nn * 8 * 4);
    float* er1  = (float*)alloc((size_t)Nn * 8 * 4);
    float* el2  = (float*)alloc((size_t)Nn * 4);
    float* er2  = (float*)alloc((size_t)Nn * 4);
    float* wal2 = (float*)alloc(64 * 4);
    float* war2 = (float*)alloc(64 * 4);
    int* row_start  = (int*)alloc((size_t)(Nn + 1) * 4);
    int* hist       = (int*)alloc((size_t)NB * PWG * 4);
    int* bucketTot  = (int*)alloc((size_t)NB * 4);
    int* bucketBase = (int*)alloc((size_t)(NB + 1) * 4);
    int* perm_src   = (int*)alloc((size_t)Ee * 4);
    unsigned* ebuf  = (unsigned*)alloc((size_t)Ee * 4);

    // CSR build (radix partition, no global atomics, hierarchical scan)
    hist_kernel<<<PWG, 256, 0, stream>>>(dst, hist, Ee, chunk, NB);
    scanA_kernel<<<NB, 256, 0, stream>>>(hist, bucketTot);
    scanB_kernel<<<1, 256, 0, stream>>>(bucketTot, bucketBase, NB, Ee);
    partition_kernel<<<PWG, 256, 0, stream>>>(src, dst, hist, bucketBase, ebuf, Ee, chunk, NB);
    bucket_csr_kernel<<<NB, 512, 0, stream>>>(ebuf, bucketBase, row_start, perm_src, Nn, Ee, NB);

    // layer 1
    conv_prep_kernel<<<129, 256, 0, stream>>>(W1, W1t, W2, al2, ar2, wal2, war2);
    gemm1_mfma_kernel<<<(Nn + 63) / 64, 256, 0, stream>>>(x, W1t, al1, ar1, h1b, el1, er1, Nn);
    agg1_kernel<<<(Nn + 3) / 4, 256, 0, stream>>>(h1b, el1, er1, row_start, perm_src, b1, hmidb, Nn);

    // layer 2
    gemm2_kernel<<<(Nn + 255) / 256, 256, 0, stream>>>(hmidb, W2, wal2, war2, h2b, el2, er2, Nn);
    agg2_kernel<<<(Nn + 3) / 4, 256, 0, stream>>>(h2b, el2, er2, row_start, perm_src, b2, out, Nn);
}